// Round 2
// baseline (1122.707 us; speedup 1.0000x reference)
//
#include <hip/hip_runtime.h>

typedef __attribute__((ext_vector_type(8))) short bf16x8;
typedef __attribute__((ext_vector_type(4))) float f32x4;
typedef __attribute__((ext_vector_type(8))) unsigned short u16x8;

static constexpr int S = 4096;
static constexpr int E = 2048;
static constexpr int F = 8192;
static constexpr int NH = 16;
static constexpr int DH = 128;

__device__ __forceinline__ unsigned short f2bf(float f) {
  unsigned u = __builtin_bit_cast(unsigned, f);
  u += 0x7FFFu + ((u >> 16) & 1u);
  return (unsigned short)(u >> 16);
}

// async global->LDS, 16B per lane. LDS dest = wave-uniform base + lane*16.
__device__ __forceinline__ void async16(const unsigned short* g, unsigned short* l) {
  __builtin_amdgcn_global_load_lds(
      (const __attribute__((address_space(1))) unsigned int*)g,
      (__attribute__((address_space(3))) unsigned int*)l, 16, 0, 0);
}

// ---------------- elementwise fp32 -> bf16 ----------------
__global__ __launch_bounds__(256) void cvt_bf16_kernel(const float* __restrict__ src,
                                                       unsigned short* __restrict__ dst) {
  int i = (blockIdx.x * 256 + threadIdx.x) * 4;
  float4 v = *(const float4*)(src + i);
  ushort4 o;
  o.x = f2bf(v.x); o.y = f2bf(v.y); o.z = f2bf(v.z); o.w = f2bf(v.w);
  *(ushort4*)(dst + i) = o;
}

// ---------------- transpose + convert: src [R][C] fp32 -> dst [C][R] bf16 ----------------
__global__ __launch_bounds__(256) void transpose_cvt(const float* __restrict__ src,
                                                     unsigned short* __restrict__ dst,
                                                     const int Rr, const int Cc) {
  __shared__ float t[32][33];
  const int c0 = blockIdx.x * 32, r0 = blockIdx.y * 32;
  const int tx = threadIdx.x, ty = threadIdx.y;
#pragma unroll
  for (int i = 0; i < 4; ++i) {
    int r = ty + i * 8;
    t[r][tx] = src[(size_t)(r0 + r) * Cc + c0 + tx];
  }
  __syncthreads();
#pragma unroll
  for (int i = 0; i < 4; ++i) {
    int cr = ty + i * 8;
    dst[(size_t)(c0 + cr) * Rr + r0 + tx] = f2bf(t[tx][cr]);
  }
}

// ---------------- GEMM: C[M][N] = A[M][K] * B^T[N][K], bf16 in, m97 structure ----------------
enum { EPI_QKV = 0, EPI_RELU = 1, EPI_OUT = 2 };

template <int EPI>
__global__ __launch_bounds__(256) void gemm_bt(
    const unsigned short* __restrict__ A, const unsigned short* __restrict__ B,
    const int K, const int N,
    const float* __restrict__ b0, const float* __restrict__ b1f, const float* __restrict__ b2f,
    unsigned short* __restrict__ o0, unsigned short* __restrict__ o1,
    unsigned short* __restrict__ o2, float* __restrict__ of) {
  __shared__ unsigned short lA[128 * 32];
  __shared__ unsigned short lB[128 * 32];
  const int tid = threadIdx.x, w = tid >> 6, lane = tid & 63;
  const int lane15 = lane & 15, l4 = lane >> 4;
  const int m0 = blockIdx.y * 128, n0 = blockIdx.x * 128;
  const int wr = w >> 1, wc = w & 1;

  // staging: chunk u covers LDS bytes u*16; row = u>>2, 16B-piece = u&3
  const int u0 = (w * 2 + 0) * 64 + lane;
  const int u1 = (w * 2 + 1) * 64 + lane;
  const unsigned short* gA0 = A + (size_t)(m0 + (u0 >> 2)) * K + (u0 & 3) * 8;
  const unsigned short* gA1 = A + (size_t)(m0 + (u1 >> 2)) * K + (u1 & 3) * 8;
  const unsigned short* gB0 = B + (size_t)(n0 + (u0 >> 2)) * K + (u0 & 3) * 8;
  const unsigned short* gB1 = B + (size_t)(n0 + (u1 >> 2)) * K + (u1 & 3) * 8;
  unsigned short* dA0 = &lA[(w * 2 + 0) * 512];
  unsigned short* dA1 = &lA[(w * 2 + 1) * 512];
  unsigned short* dB0 = &lB[(w * 2 + 0) * 512];
  unsigned short* dB1 = &lB[(w * 2 + 1) * 512];

  const unsigned short* pa[4];
  const unsigned short* pb[4];
#pragma unroll
  for (int i = 0; i < 4; ++i) {
    pa[i] = &lA[(wr * 64 + i * 16 + lane15) * 32 + l4 * 8];
    pb[i] = &lB[(wc * 64 + i * 16 + lane15) * 32 + l4 * 8];
  }

  f32x4 zero4 = {0.f, 0.f, 0.f, 0.f};
  f32x4 acc[4][4];
#pragma unroll
  for (int i = 0; i < 4; ++i)
#pragma unroll
    for (int j = 0; j < 4; ++j) acc[i][j] = zero4;

  for (int ko = 0; ko < K; ko += 32) {
    __syncthreads();
    async16(gA0 + ko, dA0);
    async16(gA1 + ko, dA1);
    async16(gB0 + ko, dB0);
    async16(gB1 + ko, dB1);
    __syncthreads();
    bf16x8 av[4], bv[4];
#pragma unroll
    for (int i = 0; i < 4; ++i) av[i] = *(const bf16x8*)pa[i];
#pragma unroll
    for (int j = 0; j < 4; ++j) bv[j] = *(const bf16x8*)pb[j];
#pragma unroll
    for (int i = 0; i < 4; ++i)
#pragma unroll
      for (int j = 0; j < 4; ++j)
        acc[i][j] = __builtin_amdgcn_mfma_f32_16x16x32_bf16(av[i], bv[j], acc[i][j], 0, 0, 0);
  }

#pragma unroll
  for (int j = 0; j < 4; ++j) {
    const int n = n0 + wc * 64 + j * 16 + lane15;
    float bias;
    if (EPI == EPI_QKV)
      bias = (n < E) ? b0[n] : ((n < 2 * E) ? b1f[n - E] : b2f[n - 2 * E]);
    else
      bias = b0[n];
#pragma unroll
    for (int i = 0; i < 4; ++i) {
      const int mr = m0 + wr * 64 + i * 16 + l4 * 4;
      f32x4 v = acc[i][j];
#pragma unroll
      for (int r = 0; r < 4; ++r) {
        const float val = v[r] + bias;
        const int m = mr + r;
        if (EPI == EPI_QKV) {
          if (n < E)            o0[(size_t)m * E + n] = f2bf(val);           // Q [S][E]
          else if (n < 2 * E)   o1[(size_t)m * E + (n - E)] = f2bf(val);     // K [S][E]
          else                  o2[(size_t)(n - 2 * E) * S + m] = f2bf(val); // V^T [H*D][S]
        } else if (EPI == EPI_RELU) {
          o0[(size_t)m * N + n] = f2bf(fmaxf(val, 0.f));
        } else {
          of[(size_t)m * N + n] = val;
        }
      }
    }
  }
}

// ---------------- flash attention, causal, 1 block = 64 q-rows x 1 head ----------------
__global__ __launch_bounds__(256) void flash_attn(const unsigned short* __restrict__ Qb,
                                                  const unsigned short* __restrict__ Kb,
                                                  const unsigned short* __restrict__ VTb,
                                                  unsigned short* __restrict__ attn) {
  const int qt = gridDim.x - 1 - blockIdx.x;  // big blocks first
  const int h = blockIdx.y;
  const int qbase = qt * 64;
  const int tid = threadIdx.x, w = tid >> 6, lane = tid & 63;
  const int lane15 = lane & 15, l4 = lane >> 4;

  __shared__ unsigned short lK[64 * 136];     // [s'][d], padded stride 136
  __shared__ unsigned short lV[128 * 72];     // [d][s_local], padded stride 72
  __shared__ unsigned short lP[4][16 * 72];   // per-wave P strip, padded

  bf16x8 aq[4];
  {
    const unsigned short* qrow = Qb + (size_t)(qbase + w * 16 + lane15) * E + h * DH + l4 * 8;
#pragma unroll
    for (int kk = 0; kk < 4; ++kk) aq[kk] = *(const bf16x8*)(qrow + kk * 32);
  }

  f32x4 zero4 = {0.f, 0.f, 0.f, 0.f};
  float mrow[4], lsum[4];
  f32x4 o[8];
#pragma unroll
  for (int r = 0; r < 4; ++r) { mrow[r] = -3e38f; lsum[r] = 0.f; }
#pragma unroll
  for (int j = 0; j < 8; ++j) o[j] = zero4;

  for (int kt = 0; kt <= qt; ++kt) {
    const int kbase = kt * 64;
    __syncthreads();
#pragma unroll
    for (int i = 0; i < 4; ++i) {  // stage K tile 64 rows x 128 d (1024 x 16B chunks)
      int c = i * 256 + tid;
      int row = c >> 4, koff = (c & 15) * 8;
      *(u16x8*)&lK[row * 136 + koff] =
          *(const u16x8*)(Kb + (size_t)(kbase + row) * E + h * DH + koff);
    }
#pragma unroll
    for (int i = 0; i < 4; ++i) {  // stage V^T tile 128 d x 64 s (1024 x 16B chunks)
      int c = i * 256 + tid;
      int d = c >> 3, soff = (c & 7) * 8;
      *(u16x8*)&lV[d * 72 + soff] =
          *(const u16x8*)(VTb + (size_t)(h * DH + d) * S + kbase + soff);
    }
    __syncthreads();

    f32x4 sacc[4];
#pragma unroll
    for (int j = 0; j < 4; ++j) sacc[j] = zero4;
#pragma unroll
    for (int kk = 0; kk < 4; ++kk)
#pragma unroll
      for (int j = 0; j < 4; ++j) {
        bf16x8 bk = *(const bf16x8*)&lK[(j * 16 + lane15) * 136 + kk * 32 + l4 * 8];
        sacc[j] = __builtin_amdgcn_mfma_f32_16x16x32_bf16(aq[kk], bk, sacc[j], 0, 0, 0);
      }

    const float scale = 0.088388347648318447f;  // 1/sqrt(128)
    float sv[4][4];
#pragma unroll
    for (int j = 0; j < 4; ++j)
#pragma unroll
      for (int r = 0; r < 4; ++r) sv[j][r] = sacc[j][r] * scale;
    if (kt == qt) {  // causal mask: only the diagonal tile needs it (BM==BN)
#pragma unroll
      for (int j = 0; j < 4; ++j) {
        int col = j * 16 + lane15;
#pragma unroll
        for (int r = 0; r < 4; ++r) {
          int row = w * 16 + l4 * 4 + r;
          if (col > row) sv[j][r] = -1e30f;
        }
      }
    }

    float alpha[4], p[4][4];
#pragma unroll
    for (int r = 0; r < 4; ++r) {
      float v = fmaxf(fmaxf(sv[0][r], sv[1][r]), fmaxf(sv[2][r], sv[3][r]));
#pragma unroll
      for (int off = 1; off < 16; off <<= 1) v = fmaxf(v, __shfl_xor(v, off, 16));
      float mn = fmaxf(mrow[r], v);
      alpha[r] = __expf(mrow[r] - mn);
      mrow[r] = mn;
    }
#pragma unroll
    for (int j = 0; j < 4; ++j)
#pragma unroll
      for (int r = 0; r < 4; ++r) p[j][r] = __expf(sv[j][r] - mrow[r]);
#pragma unroll
    for (int r = 0; r < 4; ++r) {
      float s = p[0][r] + p[1][r] + p[2][r] + p[3][r];
#pragma unroll
      for (int off = 1; off < 16; off <<= 1) s += __shfl_xor(s, off, 16);
      lsum[r] = lsum[r] * alpha[r] + s;
    }
#pragma unroll
    for (int j = 0; j < 8; ++j) {
      f32x4 t = o[j];
      t[0] *= alpha[0]; t[1] *= alpha[1]; t[2] *= alpha[2]; t[3] *= alpha[3];
      o[j] = t;
    }
    // P: C-layout -> LDS -> A-layout
#pragma unroll
    for (int j = 0; j < 4; ++j)
#pragma unroll
      for (int r = 0; r < 4; ++r)
        lP[w][(l4 * 4 + r) * 72 + j * 16 + lane15] = f2bf(p[j][r]);
    __syncthreads();
#pragma unroll
    for (int ks = 0; ks < 2; ++ks) {
      bf16x8 ap = *(const bf16x8*)&lP[w][lane15 * 72 + ks * 32 + l4 * 8];
#pragma unroll
      for (int j = 0; j < 8; ++j) {
        bf16x8 bv = *(const bf16x8*)&lV[(j * 16 + lane15) * 72 + ks * 32 + l4 * 8];
        o[j] = __builtin_amdgcn_mfma_f32_16x16x32_bf16(ap, bv, o[j], 0, 0, 0);
      }
    }
  }

  float inv[4];
#pragma unroll
  for (int r = 0; r < 4; ++r) inv[r] = 1.0f / lsum[r];
#pragma unroll
  for (int j = 0; j < 8; ++j)
#pragma unroll
    for (int r = 0; r < 4; ++r)
      attn[(size_t)(qbase + w * 16 + l4 * 4 + r) * E + h * DH + j * 16 + lane15] =
          f2bf(o[j][r] * inv[r]);
}

// ---------------- launcher ----------------
extern "C" void kernel_launch(void* const* d_in, const int* in_sizes, int n_in,
                              void* d_out, int out_size, void* d_ws, size_t ws_size,
                              hipStream_t stream) {
  (void)in_sizes; (void)n_in; (void)out_size; (void)ws_size;
  const float* emb = (const float*)d_in[0];
  const float* Wq  = (const float*)d_in[1];
  const float* bq  = (const float*)d_in[2];
  const float* Wk  = (const float*)d_in[3];
  const float* bk  = (const float*)d_in[4];
  const float* Wv  = (const float*)d_in[5];
  const float* bv  = (const float*)d_in[6];
  const float* W1  = (const float*)d_in[7];
  const float* b1  = (const float*)d_in[8];
  const float* W2  = (const float*)d_in[9];
  const float* b2  = (const float*)d_in[10];
  float* out = (float*)d_out;

  // workspace carve (152 MB) with lifetime overlays:
  //   [0,16MB)   emb_bf, reused as attn after QKV GEMM
  //   [16,88MB)  WqkvT(24)+Q(16)+K(16)+V^T(16); overlaid by hidden(64) after flash
  //   [88,120)   W1T    [120,152) W2T
  char* ws = (char*)d_ws;
  const size_t MB = 1024ull * 1024ull;
  unsigned short* embb   = (unsigned short*)(ws);
  unsigned short* attn   = embb;
  char* r1 = ws + 16 * MB;
  unsigned short* WqkvT  = (unsigned short*)(r1);
  unsigned short* Qb     = (unsigned short*)(r1 + 24 * MB);
  unsigned short* Kb     = (unsigned short*)(r1 + 40 * MB);
  unsigned short* VTb    = (unsigned short*)(r1 + 56 * MB);
  unsigned short* hidden = (unsigned short*)(r1);
  unsigned short* W1T    = (unsigned short*)(r1 + 72 * MB);
  unsigned short* W2T    = (unsigned short*)(r1 + 104 * MB);

  dim3 b256(256);
  dim3 tb(32, 8);
  cvt_bf16_kernel<<<dim3((S * E) / 1024), b256, 0, stream>>>(emb, embb);
  transpose_cvt<<<dim3(E / 32, E / 32), tb, 0, stream>>>(Wq, WqkvT, E, E);
  transpose_cvt<<<dim3(E / 32, E / 32), tb, 0, stream>>>(Wk, WqkvT + (size_t)E * E, E, E);
  transpose_cvt<<<dim3(E / 32, E / 32), tb, 0, stream>>>(Wv, WqkvT + 2ull * E * E, E, E);
  transpose_cvt<<<dim3(F / 32, E / 32), tb, 0, stream>>>(W1, W1T, E, F);
  transpose_cvt<<<dim3(E / 32, F / 32), tb, 0, stream>>>(W2, W2T, F, E);

  gemm_bt<EPI_QKV><<<dim3(3 * E / 128, S / 128), b256, 0, stream>>>(
      embb, WqkvT, E, 3 * E, bq, bk, bv, Qb, Kb, VTb, nullptr);
  flash_attn<<<dim3(S / 64, NH), b256, 0, stream>>>(Qb, Kb, VTb, attn);
  gemm_bt<EPI_RELU><<<dim3(F / 128, S / 128), b256, 0, stream>>>(
      attn, W1T, E, F, b1, nullptr, nullptr, hidden, nullptr, nullptr, nullptr);
  gemm_bt<EPI_OUT><<<dim3(E / 128, S / 128), b256, 0, stream>>>(
      hidden, W2T, F, E, b2, nullptr, nullptr, nullptr, nullptr, nullptr, out);
}